// Round 6
// baseline (332.529 us; speedup 1.0000x reference)
//
#include <hip/hip_runtime.h>

#define NN 100000                 // NUM_NODES
#define STILE 512
#define SNB ((NN + STILE - 1) / STILE)   // 196 scan tiles (< 512, fits one block-scan)

typedef float floatx4 __attribute__((ext_vector_type(4)));
typedef int   intx4   __attribute__((ext_vector_type(4)));

// ---------- Kernel 1: histogram of tokens per node (int4 NT map reads) ----------
__global__ void asl_count_kernel(const intx4* __restrict__ map4,
                                 const int* __restrict__ map,
                                 unsigned int* __restrict__ cnt, int n) {
    int n4 = n >> 2;
    int i = blockIdx.x * blockDim.x + threadIdx.x;
    int stride = gridDim.x * blockDim.x;
    for (; i < n4; i += stride) {
        intx4 m = __builtin_nontemporal_load(&map4[i]);
        atomicAdd(&cnt[m.x], 1u);
        atomicAdd(&cnt[m.y], 1u);
        atomicAdd(&cnt[m.z], 1u);
        atomicAdd(&cnt[m.w], 1u);
    }
    if (blockIdx.x == 0 && threadIdx.x < (n & 3)) {
        atomicAdd(&cnt[map[(n4 << 2) + threadIdx.x]], 1u);
    }
}

// ---------- Scan pass A: per-tile sums (coalesced, 512-wide) ----------
__global__ __launch_bounds__(STILE)
void asl_blocksum_kernel(const unsigned int* __restrict__ cnt,
                         unsigned int* __restrict__ blocksum) {
    __shared__ unsigned int sh[STILE];
    int t = threadIdx.x, b = blockIdx.x;
    int i = b * STILE + t;
    sh[t] = (i < NN) ? cnt[i] : 0u;
    __syncthreads();
    for (int off = STILE / 2; off > 0; off >>= 1) {
        if (t < off) sh[t] += sh[t + off];
        __syncthreads();
    }
    if (t == 0) blocksum[b] = sh[0];
}

// ---------- Scan pass B+C fused: each block inline-scans the 196 tile sums,
// then scans its own 512-tile and writes base/next. ----------
__global__ __launch_bounds__(STILE)
void asl_scantiles_kernel(const unsigned int* __restrict__ cnt,
                          const unsigned int* __restrict__ blocksum,
                          unsigned int* __restrict__ base,
                          unsigned int* __restrict__ next) {
    __shared__ unsigned int sh[STILE];
    int t = threadIdx.x, b = blockIdx.x;

    // inclusive scan of blocksum[0..SNB) (padded with zeros to 512)
    sh[t] = (t < SNB) ? blocksum[t] : 0u;
    __syncthreads();
    for (int off = 1; off < STILE; off <<= 1) {
        unsigned int y = (t >= off) ? sh[t - off] : 0u;
        __syncthreads();
        sh[t] += y;
        __syncthreads();
    }
    unsigned int blockoff = (b == 0) ? 0u : sh[b - 1];
    __syncthreads();                                    // before reusing sh

    int i = b * STILE + t;
    unsigned int v = (i < NN) ? cnt[i] : 0u;
    sh[t] = v;
    __syncthreads();
    for (int off = 1; off < STILE; off <<= 1) {
        unsigned int y = (t >= off) ? sh[t - off] : 0u;
        __syncthreads();
        sh[t] += y;
        __syncthreads();
    }
    unsigned int excl = blockoff + sh[t] - v;
    if (i < NN) {
        base[i] = excl;
        next[i] = excl;   // after fill, next[i] == base[i] + cnt[i]
    }
}

// ---------- Fill CSR token lists (int4 NT map reads, NT list stores) ----------
__global__ void asl_fill_kernel(const intx4* __restrict__ map4,
                                const int* __restrict__ map,
                                unsigned int* __restrict__ next,
                                int* __restrict__ list, int n) {
    int n4 = n >> 2;
    int i = blockIdx.x * blockDim.x + threadIdx.x;
    int stride = gridDim.x * blockDim.x;
    for (; i < n4; i += stride) {
        intx4 m = __builtin_nontemporal_load(&map4[i]);
        int tok = i << 2;
        unsigned int p0 = atomicAdd(&next[m.x], 1u);
        unsigned int p1 = atomicAdd(&next[m.y], 1u);
        unsigned int p2 = atomicAdd(&next[m.z], 1u);
        unsigned int p3 = atomicAdd(&next[m.w], 1u);
        __builtin_nontemporal_store(tok,     &list[p0]);
        __builtin_nontemporal_store(tok + 1, &list[p1]);
        __builtin_nontemporal_store(tok + 2, &list[p2]);
        __builtin_nontemporal_store(tok + 3, &list[p3]);
    }
    if (blockIdx.x == 0 && threadIdx.x < (n & 3)) {
        int tok = (n4 << 2) + threadIdx.x;
        list[atomicAdd(&next[map[tok]], 1u)] = tok;
    }
}

// ---------- Gather-mean: one wave per node ----------
// lane l owns float4 chunk l of the 256-float row (64x16B = 1KB/row, coalesced).
// Fast path (c <= 64, ~all nodes for Poisson(10)): single masked list load,
// indices broadcast via __shfl, unroll x8 with 4 accumulators -> 8 independent
// 1KB row loads in flight/wave. General path kept for safety.
__global__ __launch_bounds__(256)
void asl_gather_kernel(const floatx4* __restrict__ data,
                       const int* __restrict__ list,
                       const unsigned int* __restrict__ base,
                       const unsigned int* __restrict__ next,
                       floatx4* __restrict__ out, int num_nodes) {
    long long tid = (long long)blockIdx.x * blockDim.x + threadIdx.x;
    int node = (int)(tid >> 6);
    if (node >= num_nodes) return;
    int lane = (int)(tid & 63);

    unsigned int b = base[node];        // wave-uniform
    unsigned int c = next[node] - b;    // wave-uniform (cursor ended at b + cnt)

    floatx4 a0 = {0.f,0.f,0.f,0.f}, a1 = {0.f,0.f,0.f,0.f};
    floatx4 a2 = {0.f,0.f,0.f,0.f}, a3 = {0.f,0.f,0.f,0.f};

    if (__builtin_expect(c <= 64u, 1)) {
        int tl = (lane < (int)c) ? __builtin_nontemporal_load(&list[b + lane]) : 0;
        unsigned int j = 0;
        for (; j + 8 <= c; j += 8) {
            int t0 = __shfl(tl, (int)j);
            int t1 = __shfl(tl, (int)j + 1);
            int t2 = __shfl(tl, (int)j + 2);
            int t3 = __shfl(tl, (int)j + 3);
            int t4 = __shfl(tl, (int)j + 4);
            int t5 = __shfl(tl, (int)j + 5);
            int t6 = __shfl(tl, (int)j + 6);
            int t7 = __shfl(tl, (int)j + 7);
            a0 += __builtin_nontemporal_load(&data[(size_t)t0 * 64 + lane]);
            a1 += __builtin_nontemporal_load(&data[(size_t)t1 * 64 + lane]);
            a2 += __builtin_nontemporal_load(&data[(size_t)t2 * 64 + lane]);
            a3 += __builtin_nontemporal_load(&data[(size_t)t3 * 64 + lane]);
            a0 += __builtin_nontemporal_load(&data[(size_t)t4 * 64 + lane]);
            a1 += __builtin_nontemporal_load(&data[(size_t)t5 * 64 + lane]);
            a2 += __builtin_nontemporal_load(&data[(size_t)t6 * 64 + lane]);
            a3 += __builtin_nontemporal_load(&data[(size_t)t7 * 64 + lane]);
        }
        for (; j + 4 <= c; j += 4) {
            int t0 = __shfl(tl, (int)j);
            int t1 = __shfl(tl, (int)j + 1);
            int t2 = __shfl(tl, (int)j + 2);
            int t3 = __shfl(tl, (int)j + 3);
            a0 += __builtin_nontemporal_load(&data[(size_t)t0 * 64 + lane]);
            a1 += __builtin_nontemporal_load(&data[(size_t)t1 * 64 + lane]);
            a2 += __builtin_nontemporal_load(&data[(size_t)t2 * 64 + lane]);
            a3 += __builtin_nontemporal_load(&data[(size_t)t3 * 64 + lane]);
        }
        for (; j < c; ++j) {
            int t0 = __shfl(tl, (int)j);
            a0 += __builtin_nontemporal_load(&data[(size_t)t0 * 64 + lane]);
        }
    } else {
        for (unsigned int j0 = 0; j0 < c; j0 += 64) {
            unsigned int rem = min(64u, c - j0);
            int tl = (lane < (int)rem) ? __builtin_nontemporal_load(&list[b + j0 + lane]) : 0;
            unsigned int j = 0;
            for (; j + 8 <= rem; j += 8) {
                int t0 = __shfl(tl, (int)j);
                int t1 = __shfl(tl, (int)j + 1);
                int t2 = __shfl(tl, (int)j + 2);
                int t3 = __shfl(tl, (int)j + 3);
                int t4 = __shfl(tl, (int)j + 4);
                int t5 = __shfl(tl, (int)j + 5);
                int t6 = __shfl(tl, (int)j + 6);
                int t7 = __shfl(tl, (int)j + 7);
                a0 += __builtin_nontemporal_load(&data[(size_t)t0 * 64 + lane]);
                a1 += __builtin_nontemporal_load(&data[(size_t)t1 * 64 + lane]);
                a2 += __builtin_nontemporal_load(&data[(size_t)t2 * 64 + lane]);
                a3 += __builtin_nontemporal_load(&data[(size_t)t3 * 64 + lane]);
                a0 += __builtin_nontemporal_load(&data[(size_t)t4 * 64 + lane]);
                a1 += __builtin_nontemporal_load(&data[(size_t)t5 * 64 + lane]);
                a2 += __builtin_nontemporal_load(&data[(size_t)t6 * 64 + lane]);
                a3 += __builtin_nontemporal_load(&data[(size_t)t7 * 64 + lane]);
            }
            for (; j < rem; ++j) {
                int t0 = __shfl(tl, (int)j);
                a0 += __builtin_nontemporal_load(&data[(size_t)t0 * 64 + lane]);
            }
        }
    }

    float w = c ? (1.0f / (float)c) : 0.0f;
    floatx4 r = ((a0 + a1) + (a2 + a3)) * w;
    __builtin_nontemporal_store(r, &out[(size_t)node * 64 + lane]);
}

extern "C" void kernel_launch(void* const* d_in, const int* in_sizes, int n_in,
                              void* d_out, int out_size, void* d_ws, size_t ws_size,
                              hipStream_t stream) {
    const float* data = (const float*)d_in[0];   // (N, 256) fp32
    const int*   map  = (const int*)d_in[1];     // (N,) int
    // d_in[2..4] = W, b, scoring -> dead code in the reference, unused.

    const int n_tokens = in_sizes[1];            // N = 1,000,000
    float* out = (float*)d_out;                  // (NN, 256) fp32

    // workspace layout (u32 units)
    unsigned int* ws       = (unsigned int*)d_ws;
    unsigned int* cnt      = ws;                        // NN
    unsigned int* base     = ws + NN;                   // NN
    unsigned int* next     = ws + 2 * NN;               // NN
    int*          list     = (int*)(ws + 3 * NN);       // n_tokens
    unsigned int* blocksum = ws + 3 * NN + n_tokens;    // SNB

    hipMemsetAsync(cnt, 0, (size_t)NN * sizeof(unsigned int), stream);

    {
        int block = 256;
        int grid = ((n_tokens >> 2) + block - 1) / block;
        asl_count_kernel<<<grid, block, 0, stream>>>(
            (const intx4*)map, map, cnt, n_tokens);
    }
    asl_blocksum_kernel<<<SNB, STILE, 0, stream>>>(cnt, blocksum);
    asl_scantiles_kernel<<<SNB, STILE, 0, stream>>>(cnt, blocksum, base, next);
    {
        int block = 256;
        int grid = ((n_tokens >> 2) + block - 1) / block;
        asl_fill_kernel<<<grid, block, 0, stream>>>(
            (const intx4*)map, map, next, list, n_tokens);
    }
    {
        int block = 256;                                  // 4 waves/block
        long long total = (long long)NN * 64;             // one wave per node
        int grid = (int)((total + block - 1) / block);
        asl_gather_kernel<<<grid, block, 0, stream>>>(
            (const floatx4*)data, list, base, next, (floatx4*)out, NN);
    }
}